// Round 11
// baseline (437.804 us; speedup 1.0000x reference)
//
#include <hip/hip_runtime.h>

typedef __bf16 bf16;
typedef __attribute__((ext_vector_type(8))) __bf16 bf16x8;
typedef __attribute__((ext_vector_type(4))) __bf16 bf16x4;
typedef __attribute__((ext_vector_type(4))) float f32x4;

#define GLL16(gptr, lptr)                                                      \
  __builtin_amdgcn_global_load_lds(                                            \
      (const __attribute__((address_space(1))) void*)(gptr),                   \
      (__attribute__((address_space(3))) void*)(lptr), 16, 0, 0)

__device__ __forceinline__ f32x4 mfma_bf16(bf16x8 a, bf16x8 b, f32x4 c) {
  return __builtin_amdgcn_mfma_f32_16x16x32_bf16(a, b, c, 0, 0, 0);
}

// ---------------- fp32 -> bf16 convert (vectorized) ----------------
__global__ __launch_bounds__(256) void k_cvt_f32_bf16(
    const float* __restrict__ in, bf16* __restrict__ out, int n4) {
  int i = blockIdx.x * blockDim.x + threadIdx.x;
  if (i < n4) {
    f32x4 v = ((const f32x4*)in)[i];
    bf16x4 o;
    o[0] = (bf16)v[0]; o[1] = (bf16)v[1]; o[2] = (bf16)v[2]; o[3] = (bf16)v[3];
    ((bf16x4*)out)[i] = o;
  }
}

// ------------- transpose + convert: out[n][k] = (bf16)in[k][n] -------------
__global__ __launch_bounds__(256) void k_transpose_cvt(
    const float* __restrict__ in, bf16* __restrict__ out, int R, int C) {
  __shared__ float tile[64][65];
  const int t = threadIdx.x;
  const int r0 = blockIdx.y * 64, c0 = blockIdx.x * 64;
  const int tc = t & 63, tr = t >> 6;
#pragma unroll
  for (int i = 0; i < 16; ++i) {
    int r = tr + i * 4;
    tile[r][tc] = in[(size_t)(r0 + r) * C + c0 + tc];
  }
  __syncthreads();
#pragma unroll
  for (int i = 0; i < 16; ++i) {
    int r = tr + i * 4;
    out[(size_t)(c0 + r) * R + r0 + tc] = (bf16)tile[tc][r];
  }
}

// ======== 256x256-tile 8-wave bf16 GEMM, BK=64, counted-vmcnt pipeline ======
// C[M][N] = A[M][2048] * Bt[N][2048]^T + bias.  K fixed = 2048.
// MODE 1: f32 flat [M][N]; MODE 2: split head-major QKV (Q,K:[B*H][2048][128],
// V transposed VT[B*H][128][2048]).
// LDS: 2 bufs x (A 256x64 + B 256x64) bf16 = 128 KiB; XOR-swizzled rows
// (byte ^= (row&7)<<4) with inverse-swizzled global_load_lds source (rule 21).
template <int MTILES, int NTILES, int MODE>
__global__ __launch_bounds__(512, 2) void k_gemm256(
    const bf16* __restrict__ A, const bf16* __restrict__ Bt,
    const float* __restrict__ bias, void* __restrict__ C0,
    void* __restrict__ C1, void* __restrict__ C2) {
  __shared__ __align__(16) unsigned char L[131072];
  const int t = threadIdx.x, w = t >> 6, lane = t & 63;
  const int g = lane >> 4, c = lane & 15;
  const int wm = w >> 2, wn = w & 3;  // wave grid 2M x 4N; wave out = 128x64
  // XCD-chunked bijective swizzle (grid multiple of 8)
  const int nwg = MTILES * NTILES;
  const int bid = (int)blockIdx.x;
  const int wg = (bid & 7) * (nwg >> 3) + (bid >> 3);
  const int bx = wg % NTILES, by = wg / NTILES;
  const char* Ab = (const char*)A + (size_t)by * 256 * 4096;  // 4096 B/row
  const char* Bb = (const char*)Bt + (size_t)bx * 256 * 4096;

  // staging: half-tile = 128 rows x 128 B = 16 KiB; per wave 2 gll/half.
  // chunk c = j*512 + w*64 + lane -> row = j*64 + w*8 + (lane>>3),
  // lds col = (lane&7)*16, global col = ldscol ^ ((row&7)<<4)
  const int lrow = lane >> 3;
  const int lsw = ((lane & 7) * 16) ^ (lrow << 4);
  const int gofs0 = (w * 8 + lrow) * 4096 + lsw;
  const int gofs1 = gofs0 + 64 * 4096;
  const unsigned ldst0 = (unsigned)(w * 64) * 16;

#define STG_HALF(lbase, gb)                                                    \
  GLL16((gb) + gofs0, L + (lbase) + ldst0);                                    \
  GLL16((gb) + gofs1, L + (lbase) + ldst0 + 8192);

#define STG_KT(bsel, kt)                                                       \
  {                                                                            \
    const char* a_ = Ab + (size_t)(kt) * 128;                                  \
    const char* b_ = Bb + (size_t)(kt) * 128;                                  \
    STG_HALF((bsel) * 65536 + 0, a_);                                          \
    STG_HALF((bsel) * 65536 + 16384, a_ + 128 * 4096);                         \
    STG_HALF((bsel) * 65536 + 32768, b_);                                      \
    STG_HALF((bsel) * 65536 + 49152, b_ + 128 * 4096);                         \
  }

  f32x4 acc[8][4];
#pragma unroll
  for (int m = 0; m < 8; ++m)
#pragma unroll
    for (int n = 0; n < 4; ++n) acc[m][n] = (f32x4){0.f, 0.f, 0.f, 0.f};

  STG_KT(0, 0);
  STG_KT(1, 1);

  const int aswz = (c & 7) << 4;
  bf16x8 ar[4][2], br[4][2];

  for (int kt = 0; kt < 32; ++kt) {
    // data for kt is complete when only the NEXT K-tile's 8 loads remain.
    if (kt == 31) {
      asm volatile("s_waitcnt vmcnt(0)" ::: "memory");
    } else {
      asm volatile("s_waitcnt vmcnt(8)" ::: "memory");
    }
    __builtin_amdgcn_s_barrier();

    const unsigned ab = (unsigned)(kt & 1) * 65536 + (unsigned)wm * 16384;
    const unsigned bb = (unsigned)(kt & 1) * 65536 + 32768 +
                        (unsigned)(wn >> 1) * 16384;
    const int brb = (wn & 1) * 64;

    // ---- phase 0: read A[mi 0..3], B[ni 0..1]; mfma quad (0,0) ----
#pragma unroll
    for (int i = 0; i < 4; ++i) {
      const int r = i * 16 + c;
#pragma unroll
      for (int ks = 0; ks < 2; ++ks)
        ar[i][ks] = *(const bf16x8*)(L + ab + r * 128 +
                                     ((ks * 64 + g * 16) ^ aswz));
    }
#pragma unroll
    for (int n = 0; n < 2; ++n) {
      const int r = brb + n * 16 + c;
#pragma unroll
      for (int ks = 0; ks < 2; ++ks)
        br[n][ks] = *(const bf16x8*)(L + bb + r * 128 +
                                     ((ks * 64 + g * 16) ^ aswz));
    }
    __builtin_amdgcn_s_barrier();
    __builtin_amdgcn_s_setprio(1);
#pragma unroll
    for (int i = 0; i < 4; ++i)
#pragma unroll
      for (int n = 0; n < 2; ++n)
#pragma unroll
        for (int ks = 0; ks < 2; ++ks)
          acc[i][n] = mfma_bf16(ar[i][ks], br[n][ks], acc[i][n]);
    __builtin_amdgcn_s_setprio(0);
    __builtin_amdgcn_s_barrier();

    // ---- phase 1: read B[ni 2..3]; mfma quad (0,1) (A cached) ----
#pragma unroll
    for (int n = 2; n < 4; ++n) {
      const int r = brb + n * 16 + c;
#pragma unroll
      for (int ks = 0; ks < 2; ++ks)
        br[n][ks] = *(const bf16x8*)(L + bb + r * 128 +
                                     ((ks * 64 + g * 16) ^ aswz));
    }
    __builtin_amdgcn_s_barrier();
    __builtin_amdgcn_s_setprio(1);
#pragma unroll
    for (int i = 0; i < 4; ++i)
#pragma unroll
      for (int n = 2; n < 4; ++n)
#pragma unroll
        for (int ks = 0; ks < 2; ++ks)
          acc[i][n] = mfma_bf16(ar[i][ks], br[n][ks], acc[i][n]);
    __builtin_amdgcn_s_setprio(0);
    __builtin_amdgcn_s_barrier();

    // ---- phase 2: read A[mi 4..7]; mfma quad (1,0) (B cached) ----
#pragma unroll
    for (int i = 0; i < 4; ++i) {
      const int r = (4 + i) * 16 + c;
#pragma unroll
      for (int ks = 0; ks < 2; ++ks)
        ar[i][ks] = *(const bf16x8*)(L + ab + r * 128 +
                                     ((ks * 64 + g * 16) ^ aswz));
    }
    __builtin_amdgcn_s_barrier();
    __builtin_amdgcn_s_setprio(1);
#pragma unroll
    for (int i = 0; i < 4; ++i)
#pragma unroll
      for (int n = 0; n < 2; ++n)
#pragma unroll
        for (int ks = 0; ks < 2; ++ks)
          acc[4 + i][n] = mfma_bf16(ar[i][ks], br[n][ks], acc[4 + i][n]);
    __builtin_amdgcn_s_setprio(0);
    __builtin_amdgcn_s_barrier();

    // ---- phase 3: mfma quad (1,1) (all cached) ----
    __builtin_amdgcn_s_setprio(1);
#pragma unroll
    for (int i = 0; i < 4; ++i)
#pragma unroll
      for (int n = 2; n < 4; ++n)
#pragma unroll
        for (int ks = 0; ks < 2; ++ks)
          acc[4 + i][n] = mfma_bf16(ar[i][ks], br[n][ks], acc[4 + i][n]);
    __builtin_amdgcn_s_setprio(0);
    __builtin_amdgcn_s_barrier();  // all waves done reading buf[kt&1]

    if (kt + 2 < 32) STG_KT(kt & 1, kt + 2);  // refill freed buffer, async
  }

  // ---------------- epilogue ----------------
#pragma unroll
  for (int ni = 0; ni < 4; ++ni) {
    const int col = bx * 256 + wn * 64 + ni * 16 + c;
    const float bs = bias[col];
    if constexpr (MODE == 2) {
      const int sec = col >> 11, hh = (col >> 7) & 15, d = col & 127;
      bf16* sbase = (bf16*)(sec == 0 ? C0 : sec == 1 ? C1 : C2) +
                    (size_t)hh * 2048 * 128;
#pragma unroll
      for (int mi = 0; mi < 8; ++mi) {
        const int row0 = by * 256 + wm * 128 + mi * 16 + g * 4;
        const int bb2 = row0 >> 11, srow = row0 & 2047;
        if (sec == 2) {  // V transposed [bh][128][2048]
          bf16x4 pk;
#pragma unroll
          for (int r = 0; r < 4; ++r) pk[r] = (bf16)(acc[mi][ni][r] + bs);
          *(bf16x4*)(sbase + (size_t)bb2 * 16 * 2048 * 128 +
                     (size_t)d * 2048 + srow) = pk;
        } else {
#pragma unroll
          for (int r = 0; r < 4; ++r)
            sbase[((size_t)bb2 * 16 * 2048 + srow + r) * 128 + d] =
                (bf16)(acc[mi][ni][r] + bs);
        }
      }
    } else {
#pragma unroll
      for (int mi = 0; mi < 8; ++mi) {
        const int row0 = by * 256 + wm * 128 + mi * 16 + g * 4;
#pragma unroll
        for (int r = 0; r < 4; ++r)
          ((float*)C0)[(size_t)(row0 + r) * (NTILES * 256) + col] =
              acc[mi][ni][r] + bs;
      }
    }
  }
#undef STG_HALF
#undef STG_KT
}

// ---------------- bf16 GEMM (128-tile), B pre-transposed — GEMM2 ----------
template <int N, int K, int MODE>
__global__ __launch_bounds__(256) void k_gemm_bt(
    const bf16* __restrict__ A, const bf16* __restrict__ Bt,
    const float* __restrict__ bias, void* __restrict__ C0,
    void* __restrict__ C1, void* __restrict__ C2) {
  __shared__ __align__(16) unsigned char lds[16384];
  unsigned char* ldsA = lds;
  unsigned char* ldsB = lds + 8192;
  const int t = threadIdx.x, w = t >> 6, lane = t & 63;
  const int g = lane >> 4, c15 = lane & 15;
  const int wr = w >> 1, wc = w & 1;
  const int m0 = blockIdx.y * 128, n0 = blockIdx.x * 128;

  const int ch = w * 64 + lane;
  const bf16* gA0 = A + (size_t)(m0 + (ch >> 2)) * K + (ch & 3) * 8;
  const bf16* gA1 = A + (size_t)(m0 + ((ch + 256) >> 2)) * K + (ch & 3) * 8;
  const bf16* gB0 = Bt + (size_t)(n0 + (ch >> 2)) * K + (ch & 3) * 8;
  const bf16* gB1 = Bt + (size_t)(n0 + ((ch + 256) >> 2)) * K + (ch & 3) * 8;
  const unsigned l0 = (unsigned)(w * 64) * 16;

  f32x4 acc[4][4];
#pragma unroll
  for (int m = 0; m < 4; ++m)
#pragma unroll
    for (int n = 0; n < 4; ++n) acc[m][n] = (f32x4){0.f, 0.f, 0.f, 0.f};

  for (int kt = 0; kt < K / 32; ++kt) {
    GLL16(gA0, ldsA + l0);
    GLL16(gA1, ldsA + l0 + 4096);
    GLL16(gB0, ldsB + l0);
    GLL16(gB1, ldsB + l0 + 4096);
    gA0 += 32; gA1 += 32; gB0 += 32; gB1 += 32;
    __syncthreads();

    bf16x8 af[4], bfr[4];
#pragma unroll
    for (int m = 0; m < 4; ++m)
      af[m] = *(const bf16x8*)(ldsA + (wr * 64 + m * 16 + c15) * 64 + g * 16);
#pragma unroll
    for (int n = 0; n < 4; ++n)
      bfr[n] = *(const bf16x8*)(ldsB + (wc * 64 + n * 16 + c15) * 64 + g * 16);
#pragma unroll
    for (int m = 0; m < 4; ++m)
#pragma unroll
      for (int n = 0; n < 4; ++n)
        acc[m][n] = mfma_bf16(af[m], bfr[n], acc[m][n]);
    __syncthreads();
  }

#pragma unroll
  for (int n = 0; n < 4; ++n) {
    const int col = n0 + wc * 64 + n * 16 + c15;
    const float bs = bias[col];
#pragma unroll
    for (int m = 0; m < 4; ++m)
#pragma unroll
      for (int r = 0; r < 4; ++r) {
        const int row = m0 + wr * 64 + m * 16 + g * 4 + r;
        const float v = acc[m][n][r] + bs;
        if constexpr (MODE == 0)
          ((bf16*)C0)[(size_t)row * N + col] = (bf16)v;
        else
          ((float*)C0)[(size_t)row * N + col] = v;
      }
  }
}

// ---------- causal flash attention, 2-way kv-split, LDS double-buffered ----
__global__ __launch_bounds__(256) void k_attn(
    const bf16* __restrict__ Qb, const bf16* __restrict__ Kb,
    const bf16* __restrict__ VT, bf16* __restrict__ ctx,
    bf16* __restrict__ oP, float* __restrict__ mlP) {
  __shared__ __align__(16) unsigned char SK[2][16384];  // K[64][128] swz
  __shared__ __align__(16) unsigned char SV[2][16384];  // VT[128][64] swz
  __shared__ __align__(16) unsigned char P[4][2048];    // per-wave P tile
  const int t = threadIdx.x, w = t >> 6, lane = t & 63;
  const int g = lane >> 4, c = lane & 15;
  const int cswz = (c & 7) << 4;
  const int L = (int)blockIdx.x;            // 0..1023
  const int bh = (L & 7) + 8 * (L >> 8);    // same bh -> same XCD (L%8 const)
  const int role = (L >> 3) & 31;
  const int b = bh >> 4, h = bh & 15;
  const size_t hb = (size_t)bh * 2048 * 128;
  const bf16* Qh = Qb + hb;
  const char* Khb = (const char*)(Kb + hb);
  const char* Vhb = (const char*)(VT + hb);
  const float sc = 0.08838834764831845f * 1.4426950408889634f;  // scale*log2e

  int kOff[4], vOff[4];
#pragma unroll
  for (int i = 0; i < 4; ++i) {
    const int kr = i * 4 + (lane >> 4);
    kOff[i] = kr * 256 + (((lane & 15) * 16) ^ ((kr & 7) << 4));
    const int vr = lane >> 3;
    vOff[i] = (w * 32 + i * 8 + vr) * 4096 + (((lane & 7) * 16) ^ (vr << 4));
  }

#define STAGE_TILE(sel, kv0)                                                   \
  {                                                                            \
    const char* kb_ = Khb + (size_t)(kv0) * 256 + w * 4096;                    \
    const char* vb_ = Vhb + (size_t)(kv0) * 2;                                 \
    GLL16(kb_ + kOff[0], &SK[sel][(w * 16 + 0) * 256]);                        \
    GLL16(kb_ + kOff[1], &SK[sel][(w * 16 + 4) * 256]);                        \
    GLL16(kb_ + kOff[2], &SK[sel][(w * 16 + 8) * 256]);                        \
    GLL16(kb_ + kOff[3], &SK[sel][(w * 16 + 12) * 256]);                       \
    GLL16(vb_ + vOff[0], &SV[sel][(w * 32 + 0) * 128]);                        \
    GLL16(vb_ + vOff[1], &SV[sel][(w * 32 + 8) * 128]);                        \
    GLL16(vb_ + vOff[2], &SV[sel][(w * 32 + 16) * 128]);                       \
    GLL16(vb_ + vOff[3], &SV[sel][(w * 32 + 24) * 128]);                       \
  }

  const int nph = (role < 16) ? 1 : 2;
  for (int ph = 0; ph < nph; ++ph) {
    int qt, kv_begin, kv_end, mode;  // mode: 0=ctx, 1=slot0, 2=slot1
    if (role < 16) {
      qt = 31 - role; kv_begin = 0; kv_end = 16; mode = 1;
    } else if (ph == 0) {
      qt = 31 - (role - 16); kv_begin = 16; kv_end = qt + 1; mode = 2;
    } else {
      qt = role - 16; kv_begin = 0; kv_end = qt + 1; mode = 0;
    }
    const int q0 = qt * 64;
    const int qb = q0 + w * 16;

    bf16x8 qf[4];
    {
      const bf16* qp = Qh + (size_t)(qb + c) * 128;
#pragma unroll
      for (int s = 0; s < 4; ++s) qf[s] = *(const bf16x8*)(qp + s * 32 + g * 8);
    }

    f32x4 o[8];
#pragma unroll
    for (int n = 0; n < 8; ++n) o[n] = (f32x4){0.f, 0.f, 0.f, 0.f};
    float mrun[4] = {-3e38f, -3e38f, -3e38f, -3e38f};
    float lrun[4] = {0.f, 0.f, 0.f, 0.f};

    __syncthreads();
    STAGE_TILE(0, kv_begin * 64);
    int cur = 0;

    for (int kt = kv_begin; kt < kv_end; ++kt) {
      const int kv0 = kt * 64;
      __syncthreads();
      if (kt + 1 < kv_end) STAGE_TILE(cur ^ 1, (kt + 1) * 64);

      float p[4][4];
      float mt[4] = {-3e38f, -3e38f, -3e38f, -3e38f};
      const bool diag = (kv0 == q0);
#pragma unroll
      for (int tt = 0; tt < 4; ++tt) {
        f32x4 s4 = (f32x4){0.f, 0.f, 0.f, 0.f};
        const unsigned char* kl = &SK[cur][(tt * 16 + c) * 256];
        __builtin_amdgcn_s_setprio(1);
#pragma unroll
        for (int s = 0; s < 4; ++s) {
          bf16x8 kf = *(const bf16x8*)(kl + ((s * 64 + g * 16) ^ cswz));
          s4 = mfma_bf16(qf[s], kf, s4);
        }
        __builtin_amdgcn_s_setprio(0);
        const int kvi = kv0 + tt * 16 + c;
#pragma unroll
        for (int r = 0; r < 4; ++r) {
          float v = s4[r] * sc;
          if (diag) {
            const int qr = qb + g * 4 + r;
            v = (kvi <= qr) ? v : -1e30f;
          }
          p[tt][r] = v;
          mt[r] = fmaxf(mt[r], v);
        }
      }
#pragma unroll
      for (int r = 0; r < 4; ++r) {
        float m = mt[r];
        m = fmaxf(m, __shfl_xor(m, 1));
        m = fmaxf(m, __shfl_xor(m, 2));
        m = fmaxf(m, __shfl_xor(m, 4));
        m = fmaxf(m, __shfl_xor(m, 8));
        mt[r] = m;
      }
      float corr[4];
#pragma unroll
      for (int r = 0; r < 4; ++r) {
        const float mn = fmaxf(mrun[r], mt[r]);
        corr[r] = exp2f(mrun[r] - mn);
        mrun[r] = mn;
      }
#pragma unroll
      for (int r = 0; r < 4; ++r) {
        float s = 0.f;
#pragma unroll
        for (int tt = 0; tt < 4; ++tt) {
          const float e = exp2f(p[tt][r] - mrun[r]);
          p[tt][r] = e;
          s += e;
        }
        s += __shfl_xor(s, 1);
        s += __shfl_xor(s, 2);
        s += __shfl_xor(s, 4);
        s += __shfl_xor(s, 8);
        lrun[r] = lrun[r] * corr[r] + s;
      }
#pragma unroll
      for (int n = 0; n < 8; ++n)
#pragma unroll
        for (int r = 0; r < 4; ++r) o[n][r] *= corr[r];

#pragma unroll
      for (int tt = 0; tt < 4; ++tt)
#pragma unroll
        for (int r = 0; r < 4; ++r) {
          const int row = g * 4 + r;
          const int colb = (tt * 16 + c) * 2;
          *(bf16*)(&P[w][row * 128 + (colb ^ ((row & 7) << 4))]) =
              (bf16)p[tt][r];
        }

#pragma unroll
      for (int ks = 0; ks < 2; ++ks) {
        bf16x8 pa = *(const bf16x8*)(&P[w][c * 128 + ((ks * 64 + g * 16) ^ cswz)]);
        __builtin_amdgcn_s_setprio(1);
#pragma unroll
        for (int n = 0; n < 8; ++n) {
          bf16x8 vb = *(const bf16x8*)(&SV[cur][(n * 16 + c) * 128 +
                                                ((ks * 64 + g * 16) ^ cswz)]);
          o[n] = mfma_bf16(pa, vb, o[n]);
        }
        __builtin_amdgcn_s_setprio(0);
      }
      cur ^= 1;
    }

    if (mode == 0) {
      float inv[4];
#pragma unroll
      for (int r = 0; r < 4; ++r) inv[r] = 1.0f / lrun[r];
#pragma unroll
      for (int n = 0; n < 8; ++n)
#pragma unroll
        for (int r = 0; r < 4; ++r) {
          const int row = qb + g * 4 + r;
          ctx[(size_t)(b * 2048 + row) * 2048 + h * 128 + n * 16 + c] =
              (bf16)(o[n][r] * inv[r]);
        }
    } else {
      const int slot = mode - 1;
      const size_t pb = ((size_t)(bh * 16 + (qt - 16)) * 2 + slot);
      bf16* op = oP + pb * 64 * 128;
#pragma unroll
      for (int n = 0; n < 8; ++n)
#pragma unroll
        for (int r = 0; r < 4; ++r) {
          const int row = w * 16 + g * 4 + r;
          op[(size_t)row * 128 + n * 16 + c] = (bf16)o[n][r];
        }
      if (c == 0) {
        float* mp = mlP + pb * 2 * 64;
#pragma unroll
        for (int r = 0; r < 4; ++r) {
          const int row = w * 16 + g * 4 + r;
          mp[row] = mrun[r];
          mp[64 + row] = lrun[r];
        }
      }
    }
  }
#undef STAGE_TILE
}

// ---------------- merge two kv-split partials -> ctx ----------------
__global__ __launch_bounds__(256) void k_merge(const bf16* __restrict__ oP,
                                               const float* __restrict__ mlP,
                                               bf16* __restrict__ ctx) {
  const int bh = blockIdx.y, qt16 = blockIdx.x;
  const int t = threadIdx.x;
  const int row = t >> 2, qq = t & 3;
  const size_t base = (size_t)(bh * 16 + qt16) * 2;
  const float mA = mlP[(base + 0) * 128 + row], lA = mlP[(base + 0) * 128 + 64 + row];
  const float mB = mlP[(base + 1) * 128 + row], lB = mlP[(base + 1) * 128 + 64 + row];
  const float m = fmaxf(mA, mB);
  const float wA = exp2f(mA - m), wB = exp2f(mB - m);
  const float inv = 1.0f / (lA * wA + lB * wB);
  const bf16* pA = oP + (base + 0) * 64 * 128 + row * 128 + qq * 32;
  const bf16* pB = oP + (base + 1) * 64 * 128 + row * 128 + qq * 32;
  const int b = bh >> 4, h = bh & 15;
  const int srow = (16 + qt16) * 64 + row;
  bf16* po = ctx + (size_t)(b * 2048 + srow) * 2048 + h * 128 + qq * 32;
#pragma unroll
  for (int i = 0; i < 4; ++i) {
    bf16x8 a = *(const bf16x8*)(pA + i * 8);
    bf16x8 bb = *(const bf16x8*)(pB + i * 8);
    bf16x8 r;
#pragma unroll
    for (int j = 0; j < 8; ++j)
      r[j] = (bf16)(((float)a[j] * wA + (float)bb[j] * wB) * inv);
    *(bf16x8*)(po + i * 8) = r;
  }
}

extern "C" void kernel_launch(void* const* d_in, const int* in_sizes, int n_in,
                              void* d_out, int out_size, void* d_ws,
                              size_t ws_size, hipStream_t stream) {
  const float* x = (const float*)d_in[0];       // [2,2048,2048]
  const float* qkvw = (const float*)d_in[1];    // [2048,6144]
  const float* qkvb = (const float*)d_in[2];    // [6144]
  const float* ow = (const float*)d_in[3];      // [2048,2048]
  const float* ob = (const float*)d_in[4];      // [2048]
  float* out = (float*)d_out;                   // [2,2048,2048] fp32

  char* ws = (char*)d_ws;
  bf16* xb = (bf16*)(ws);                  // 16.78 MB
  bf16* wqT = (bf16*)(ws + 16777216);      // 25.17 MB (dead after GEMM1)
  bf16* owT = (bf16*)(ws + 41943040);      // 8.39 MB
  bf16* Qbuf = (bf16*)(ws + 50331648);     // 16.78 MB  [B*H][2048][128]
  bf16* Kbuf = (bf16*)(ws + 67108864);     // 16.78 MB  [B*H][2048][128]
  bf16* VTbuf = (bf16*)(ws + 83886080);    // 16.78 MB  [B*H][128][2048]
  bf16* ctxb = xb;                          // reuse: xb dead after GEMM1
  bf16* oP = wqT;                           // reuse: 16.78 MB partials
  float* mlP = (float*)(ws + 16777216 + 16777216);  // 1.05 MB (within wqT)

  // 1) x -> bf16
  k_cvt_f32_bf16<<<8192, 256, 0, stream>>>(x, xb, 2097152);
  // 2) weight transposes (B^T layout for GEMM)
  k_transpose_cvt<<<dim3(96, 32), 256, 0, stream>>>(qkvw, wqT, 2048, 6144);
  k_transpose_cvt<<<dim3(32, 32), 256, 0, stream>>>(ow, owT, 2048, 2048);
  // 3) QKV projection: 256^2-tile 8-wave pipeline, split head-major epilogue
  k_gemm256<16, 24, 2><<<384, 512, 0, stream>>>(
      xb, wqT, qkvb, (void*)Qbuf, (void*)Kbuf, (void*)VTbuf);
  // 4) causal flash attention, 2-way kv-split, LDS dbuf pipeline
  k_attn<<<1024, 256, 0, stream>>>(Qbuf, Kbuf, VTbuf, ctxb, oP, mlP);
  // 4b) merge partials for long q-tiles
  k_merge<<<dim3(16, 32), 256, 0, stream>>>(oP, mlP, ctxb);
  // 5) output projection: out fp32 = ctxb @ owT^T + ob
  k_gemm_bt<2048, 2048, 1><<<dim3(16, 32), 256, 0, stream>>>(
      ctxb, owT, ob, (void*)out, nullptr, nullptr);
}

// Round 12
// 418.896 us; speedup vs baseline: 1.0451x; 1.0451x over previous
//
#include <hip/hip_runtime.h>

typedef __bf16 bf16;
typedef __attribute__((ext_vector_type(8))) __bf16 bf16x8;
typedef __attribute__((ext_vector_type(4))) __bf16 bf16x4;
typedef __attribute__((ext_vector_type(4))) float f32x4;

#define GLL16(gptr, lptr)                                                      \
  __builtin_amdgcn_global_load_lds(                                            \
      (const __attribute__((address_space(1))) void*)(gptr),                   \
      (__attribute__((address_space(3))) void*)(lptr), 16, 0, 0)

__device__ __forceinline__ f32x4 mfma_bf16(bf16x8 a, bf16x8 b, f32x4 c) {
  return __builtin_amdgcn_mfma_f32_16x16x32_bf16(a, b, c, 0, 0, 0);
}

// ---------------- fp32 -> bf16 convert (vectorized) ----------------
__global__ __launch_bounds__(256) void k_cvt_f32_bf16(
    const float* __restrict__ in, bf16* __restrict__ out, int n4) {
  int i = blockIdx.x * blockDim.x + threadIdx.x;
  if (i < n4) {
    f32x4 v = ((const f32x4*)in)[i];
    bf16x4 o;
    o[0] = (bf16)v[0]; o[1] = (bf16)v[1]; o[2] = (bf16)v[2]; o[3] = (bf16)v[3];
    ((bf16x4*)out)[i] = o;
  }
}

// ------------- transpose + convert: out[n][k] = (bf16)in[k][n] -------------
__global__ __launch_bounds__(256) void k_transpose_cvt(
    const float* __restrict__ in, bf16* __restrict__ out, int R, int C) {
  __shared__ float tile[64][65];
  const int t = threadIdx.x;
  const int r0 = blockIdx.y * 64, c0 = blockIdx.x * 64;
  const int tc = t & 63, tr = t >> 6;
#pragma unroll
  for (int i = 0; i < 16; ++i) {
    int r = tr + i * 4;
    tile[r][tc] = in[(size_t)(r0 + r) * C + c0 + tc];
  }
  __syncthreads();
#pragma unroll
  for (int i = 0; i < 16; ++i) {
    int r = tr + i * 4;
    out[(size_t)(c0 + r) * R + r0 + tc] = (bf16)tile[tc][r];
  }
}

// ---------------- bf16 GEMM, B pre-transposed (Bt[N][K]) ----------------
// MODE 0: bf16 flat [M][N]; MODE 1: f32 flat [M][N];
// MODE 2: split head-major QKV — Q,K:[B*H][2048][128]; V TRANSPOSED:
//         VT[B*H][128][2048] so attention staging reads are contiguous.
// LDS rows (64 B) are stored with 16B-granule XOR swizzle: granule ^= (row>>1)&3
// (rule 21: inverse-swizzled global source + same XOR on ds_read) -> the
// 16-lane read phase covers all 8 granule-slots with 2 lanes each (2-way=free)
// instead of 8-way.
template <int N, int K, int MODE>
__global__ __launch_bounds__(256) void k_gemm_bt(
    const bf16* __restrict__ A, const bf16* __restrict__ Bt,
    const float* __restrict__ bias, void* __restrict__ C0,
    void* __restrict__ C1, void* __restrict__ C2) {
  __shared__ __align__(16) unsigned char lds[16384];
  unsigned char* ldsA = lds;
  unsigned char* ldsB = lds + 8192;
  const int t = threadIdx.x, w = t >> 6, lane = t & 63;
  const int g = lane >> 4, c15 = lane & 15;
  const int wr = w >> 1, wc = w & 1;
  const int m0 = blockIdx.y * 128, n0 = blockIdx.x * 128;

  // staging chunks: chunk ch (16B) -> row ch>>2; source granule XOR (row>>1)&3
  const int ch = w * 64 + lane;
  const int gsw = (((ch & 3) ^ ((ch >> 3) & 3))) * 8;  // bf16 elements
  const bf16* gA0 = A + (size_t)(m0 + (ch >> 2)) * K + gsw;
  const bf16* gA1 = A + (size_t)(m0 + ((ch + 256) >> 2)) * K + gsw;
  const bf16* gB0 = Bt + (size_t)(n0 + (ch >> 2)) * K + gsw;
  const bf16* gB1 = Bt + (size_t)(n0 + ((ch + 256) >> 2)) * K + gsw;
  const unsigned l0 = (unsigned)(w * 64) * 16;
  const int rs = (c15 >> 1) & 3;  // read-side XOR (row = ..+c15, base%8==0)

  f32x4 acc[4][4];
#pragma unroll
  for (int m = 0; m < 4; ++m)
#pragma unroll
    for (int n = 0; n < 4; ++n) acc[m][n] = (f32x4){0.f, 0.f, 0.f, 0.f};

  for (int kt = 0; kt < K / 32; ++kt) {
    GLL16(gA0, ldsA + l0);
    GLL16(gA1, ldsA + l0 + 4096);
    GLL16(gB0, ldsB + l0);
    GLL16(gB1, ldsB + l0 + 4096);
    gA0 += 32; gA1 += 32; gB0 += 32; gB1 += 32;
    __syncthreads();  // drains vmcnt -> tile visible

    bf16x8 af[4], bfr[4];
#pragma unroll
    for (int m = 0; m < 4; ++m)
      af[m] = *(const bf16x8*)(ldsA + (wr * 64 + m * 16 + c15) * 64 +
                               ((g ^ rs) * 16));
#pragma unroll
    for (int n = 0; n < 4; ++n)
      bfr[n] = *(const bf16x8*)(ldsB + (wc * 64 + n * 16 + c15) * 64 +
                                ((g ^ rs) * 16));
#pragma unroll
    for (int m = 0; m < 4; ++m)
#pragma unroll
      for (int n = 0; n < 4; ++n)
        acc[m][n] = mfma_bf16(af[m], bfr[n], acc[m][n]);
    __syncthreads();  // all waves done reading before next stage
  }

  bf16* sbase = nullptr;
  int sec = 0;
  if constexpr (MODE == 2) {
    sec = n0 >> 11;
    const int hh = (n0 >> 7) & 15;
    sbase = (bf16*)(sec == 0 ? C0 : sec == 1 ? C1 : C2) +
            (size_t)hh * 2048 * 128;
  }

#pragma unroll
  for (int n = 0; n < 4; ++n) {
    const int col = n0 + wc * 64 + n * 16 + c15;
    const float bs = bias[col];
#pragma unroll
    for (int m = 0; m < 4; ++m) {
      if (MODE == 2 && sec == 2) {
        // V: transposed [bh][128][2048]; 4 consecutive srow -> bf16x4 store
        const int row = m0 + wr * 64 + m * 16 + g * 4;
        const int bb = row >> 11, srow = row & 2047;
        const int d = wc * 64 + n * 16 + c15;
        bf16x4 pk;
#pragma unroll
        for (int r = 0; r < 4; ++r) pk[r] = (bf16)(acc[m][n][r] + bs);
        *(bf16x4*)(sbase + (size_t)bb * 16 * 2048 * 128 + (size_t)d * 2048 +
                   srow) = pk;
      } else {
#pragma unroll
        for (int r = 0; r < 4; ++r) {
          const int row = m0 + wr * 64 + m * 16 + g * 4 + r;
          const float v = acc[m][n][r] + bs;
          if constexpr (MODE == 0) {
            ((bf16*)C0)[(size_t)row * N + col] = (bf16)v;
          } else if constexpr (MODE == 1) {
            ((float*)C0)[(size_t)row * N + col] = v;
          } else {
            const int bb = row >> 11, srow = row & 2047;
            const int d = wc * 64 + n * 16 + c15;
            sbase[((size_t)bb * 16 * 2048 + srow) * 128 + d] = (bf16)v;
          }
        }
      }
    }
  }
}

// ---------- causal flash attention, 2-way kv-split, LDS double-buffered ----
// Qb/Kb: [B*H][2048][128] bf16 ; VT: [B*H][128][2048] bf16 (transposed)
// ctx: [B*S][2048] bf16
// oP: [bh][qt16][slot][64][128] bf16 ; mlP: [bh][qt16][slot][2][64] f32
__global__ __launch_bounds__(256) void k_attn(
    const bf16* __restrict__ Qb, const bf16* __restrict__ Kb,
    const bf16* __restrict__ VT, bf16* __restrict__ ctx,
    bf16* __restrict__ oP, float* __restrict__ mlP) {
  __shared__ __align__(16) unsigned char SK[2][16384];  // K[64][128] swz
  __shared__ __align__(16) unsigned char SV[2][16384];  // VT[128][64] swz
  __shared__ __align__(16) unsigned char P[4][2048];    // per-wave P tile
  const int t = threadIdx.x, w = t >> 6, lane = t & 63;
  const int g = lane >> 4, c = lane & 15;
  const int cswz = (c & 7) << 4;
  const int L = (int)blockIdx.x;            // 0..1023
  const int bh = (L & 7) + 8 * (L >> 8);    // same bh -> same XCD (L%8 const)
  const int role = (L >> 3) & 31;
  const int b = bh >> 4, h = bh & 15;
  const size_t hb = (size_t)bh * 2048 * 128;
  const bf16* Qh = Qb + hb;
  const char* Khb = (const char*)(Kb + hb);
  const char* Vhb = (const char*)(VT + hb);
  const float sc = 0.08838834764831845f * 1.4426950408889634f;  // scale*log2e

  int kOff[4], vOff[4];
#pragma unroll
  for (int i = 0; i < 4; ++i) {
    const int kr = i * 4 + (lane >> 4);
    kOff[i] = kr * 256 + (((lane & 15) * 16) ^ ((kr & 7) << 4));
    const int vr = lane >> 3;
    vOff[i] = (w * 32 + i * 8 + vr) * 4096 + (((lane & 7) * 16) ^ (vr << 4));
  }

#define STAGE_TILE(sel, kv0)                                                   \
  {                                                                            \
    const char* kb_ = Khb + (size_t)(kv0) * 256 + w * 4096;                    \
    const char* vb_ = Vhb + (size_t)(kv0) * 2;                                 \
    GLL16(kb_ + kOff[0], &SK[sel][(w * 16 + 0) * 256]);                        \
    GLL16(kb_ + kOff[1], &SK[sel][(w * 16 + 4) * 256]);                        \
    GLL16(kb_ + kOff[2], &SK[sel][(w * 16 + 8) * 256]);                        \
    GLL16(kb_ + kOff[3], &SK[sel][(w * 16 + 12) * 256]);                       \
    GLL16(vb_ + vOff[0], &SV[sel][(w * 32 + 0) * 128]);                        \
    GLL16(vb_ + vOff[1], &SV[sel][(w * 32 + 8) * 128]);                        \
    GLL16(vb_ + vOff[2], &SV[sel][(w * 32 + 16) * 128]);                       \
    GLL16(vb_ + vOff[3], &SV[sel][(w * 32 + 24) * 128]);                       \
  }

  const int nph = (role < 16) ? 1 : 2;
  for (int ph = 0; ph < nph; ++ph) {
    int qt, kv_begin, kv_end, mode;  // mode: 0=ctx, 1=slot0, 2=slot1
    if (role < 16) {
      qt = 31 - role; kv_begin = 0; kv_end = 16; mode = 1;
    } else if (ph == 0) {
      qt = 31 - (role - 16); kv_begin = 16; kv_end = qt + 1; mode = 2;
    } else {
      qt = role - 16; kv_begin = 0; kv_end = qt + 1; mode = 0;
    }
    const int q0 = qt * 64;
    const int qb = q0 + w * 16;

    bf16x8 qf[4];
    {
      const bf16* qp = Qh + (size_t)(qb + c) * 128;
#pragma unroll
      for (int s = 0; s < 4; ++s) qf[s] = *(const bf16x8*)(qp + s * 32 + g * 8);
    }

    f32x4 o[8];
#pragma unroll
    for (int n = 0; n < 8; ++n) o[n] = (f32x4){0.f, 0.f, 0.f, 0.f};
    float mrun[4] = {-3e38f, -3e38f, -3e38f, -3e38f};
    float lrun[4] = {0.f, 0.f, 0.f, 0.f};

    __syncthreads();
    STAGE_TILE(0, kv_begin * 64);
    int cur = 0;

    for (int kt = kv_begin; kt < kv_end; ++kt) {
      const int kv0 = kt * 64;
      __syncthreads();
      if (kt + 1 < kv_end) STAGE_TILE(cur ^ 1, (kt + 1) * 64);

      float p[4][4];
      float mt[4] = {-3e38f, -3e38f, -3e38f, -3e38f};
      const bool diag = (kv0 == q0);
#pragma unroll
      for (int tt = 0; tt < 4; ++tt) {
        f32x4 s4 = (f32x4){0.f, 0.f, 0.f, 0.f};
        const unsigned char* kl = &SK[cur][(tt * 16 + c) * 256];
        __builtin_amdgcn_s_setprio(1);
#pragma unroll
        for (int s = 0; s < 4; ++s) {
          bf16x8 kf = *(const bf16x8*)(kl + ((s * 64 + g * 16) ^ cswz));
          s4 = mfma_bf16(qf[s], kf, s4);
        }
        __builtin_amdgcn_s_setprio(0);
        const int kvi = kv0 + tt * 16 + c;
#pragma unroll
        for (int r = 0; r < 4; ++r) {
          float v = s4[r] * sc;
          if (diag) {
            const int qr = qb + g * 4 + r;
            v = (kvi <= qr) ? v : -1e30f;
          }
          p[tt][r] = v;
          mt[r] = fmaxf(mt[r], v);
        }
      }
#pragma unroll
      for (int r = 0; r < 4; ++r) {
        float m = mt[r];
        m = fmaxf(m, __shfl_xor(m, 1));
        m = fmaxf(m, __shfl_xor(m, 2));
        m = fmaxf(m, __shfl_xor(m, 4));
        m = fmaxf(m, __shfl_xor(m, 8));
        mt[r] = m;
      }
      float corr[4];
#pragma unroll
      for (int r = 0; r < 4; ++r) {
        const float mn = fmaxf(mrun[r], mt[r]);
        corr[r] = exp2f(mrun[r] - mn);
        mrun[r] = mn;
      }
#pragma unroll
      for (int r = 0; r < 4; ++r) {
        float s = 0.f;
#pragma unroll
        for (int tt = 0; tt < 4; ++tt) {
          const float e = exp2f(p[tt][r] - mrun[r]);
          p[tt][r] = e;
          s += e;
        }
        s += __shfl_xor(s, 1);
        s += __shfl_xor(s, 2);
        s += __shfl_xor(s, 4);
        s += __shfl_xor(s, 8);
        lrun[r] = lrun[r] * corr[r] + s;
      }
#pragma unroll
      for (int n = 0; n < 8; ++n)
#pragma unroll
        for (int r = 0; r < 4; ++r) o[n][r] *= corr[r];

#pragma unroll
      for (int tt = 0; tt < 4; ++tt)
#pragma unroll
        for (int r = 0; r < 4; ++r) {
          const int row = g * 4 + r;
          const int colb = (tt * 16 + c) * 2;
          *(bf16*)(&P[w][row * 128 + (colb ^ ((row & 7) << 4))]) =
              (bf16)p[tt][r];
        }

#pragma unroll
      for (int ks = 0; ks < 2; ++ks) {
        bf16x8 pa = *(const bf16x8*)(&P[w][c * 128 + ((ks * 64 + g * 16) ^ cswz)]);
        __builtin_amdgcn_s_setprio(1);
#pragma unroll
        for (int n = 0; n < 8; ++n) {
          bf16x8 vb = *(const bf16x8*)(&SV[cur][(n * 16 + c) * 128 +
                                                ((ks * 64 + g * 16) ^ cswz)]);
          o[n] = mfma_bf16(pa, vb, o[n]);
        }
        __builtin_amdgcn_s_setprio(0);
      }
      cur ^= 1;
    }

    if (mode == 0) {
      float inv[4];
#pragma unroll
      for (int r = 0; r < 4; ++r) inv[r] = 1.0f / lrun[r];
#pragma unroll
      for (int n = 0; n < 8; ++n)
#pragma unroll
        for (int r = 0; r < 4; ++r) {
          const int row = qb + g * 4 + r;
          ctx[(size_t)(b * 2048 + row) * 2048 + h * 128 + n * 16 + c] =
              (bf16)(o[n][r] * inv[r]);
        }
    } else {
      const int slot = mode - 1;
      const size_t pb = ((size_t)(bh * 16 + (qt - 16)) * 2 + slot);
      bf16* op = oP + pb * 64 * 128;
#pragma unroll
      for (int n = 0; n < 8; ++n)
#pragma unroll
        for (int r = 0; r < 4; ++r) {
          const int row = w * 16 + g * 4 + r;
          op[(size_t)row * 128 + n * 16 + c] = (bf16)o[n][r];
        }
      if (c == 0) {
        float* mp = mlP + pb * 2 * 64;
#pragma unroll
        for (int r = 0; r < 4; ++r) {
          const int row = w * 16 + g * 4 + r;
          mp[row] = mrun[r];
          mp[64 + row] = lrun[r];
        }
      }
    }
  }
#undef STAGE_TILE
}

// ---------------- merge two kv-split partials -> ctx ----------------
__global__ __launch_bounds__(256) void k_merge(const bf16* __restrict__ oP,
                                               const float* __restrict__ mlP,
                                               bf16* __restrict__ ctx) {
  const int bh = blockIdx.y, qt16 = blockIdx.x;
  const int t = threadIdx.x;
  const int row = t >> 2, qq = t & 3;
  const size_t base = (size_t)(bh * 16 + qt16) * 2;
  const float mA = mlP[(base + 0) * 128 + row], lA = mlP[(base + 0) * 128 + 64 + row];
  const float mB = mlP[(base + 1) * 128 + row], lB = mlP[(base + 1) * 128 + 64 + row];
  const float m = fmaxf(mA, mB);
  const float wA = exp2f(mA - m), wB = exp2f(mB - m);
  const float inv = 1.0f / (lA * wA + lB * wB);
  const bf16* pA = oP + (base + 0) * 64 * 128 + row * 128 + qq * 32;
  const bf16* pB = oP + (base + 1) * 64 * 128 + row * 128 + qq * 32;
  const int b = bh >> 4, h = bh & 15;
  const int srow = (16 + qt16) * 64 + row;
  bf16* po = ctx + (size_t)(b * 2048 + srow) * 2048 + h * 128 + qq * 32;
#pragma unroll
  for (int i = 0; i < 4; ++i) {
    bf16x8 a = *(const bf16x8*)(pA + i * 8);
    bf16x8 bb = *(const bf16x8*)(pB + i * 8);
    bf16x8 r;
#pragma unroll
    for (int j = 0; j < 8; ++j)
      r[j] = (bf16)(((float)a[j] * wA + (float)bb[j] * wB) * inv);
    *(bf16x8*)(po + i * 8) = r;
  }
}

extern "C" void kernel_launch(void* const* d_in, const int* in_sizes, int n_in,
                              void* d_out, int out_size, void* d_ws,
                              size_t ws_size, hipStream_t stream) {
  const float* x = (const float*)d_in[0];       // [2,2048,2048]
  const float* qkvw = (const float*)d_in[1];    // [2048,6144]
  const float* qkvb = (const float*)d_in[2];    // [6144]
  const float* ow = (const float*)d_in[3];      // [2048,2048]
  const float* ob = (const float*)d_in[4];      // [2048]
  float* out = (float*)d_out;                   // [2,2048,2048] fp32

  char* ws = (char*)d_ws;
  bf16* xb = (bf16*)(ws);                  // 16.78 MB
  bf16* wqT = (bf16*)(ws + 16777216);      // 25.17 MB (dead after GEMM1)
  bf16* owT = (bf16*)(ws + 41943040);      // 8.39 MB
  bf16* Qbuf = (bf16*)(ws + 50331648);     // 16.78 MB  [B*H][2048][128]
  bf16* Kbuf = (bf16*)(ws + 67108864);     // 16.78 MB  [B*H][2048][128]
  bf16* VTbuf = (bf16*)(ws + 83886080);    // 16.78 MB  [B*H][128][2048]
  bf16* ctxb = xb;                          // reuse: xb dead after GEMM1
  bf16* oP = wqT;                           // reuse: 16.78 MB partials
  float* mlP = (float*)(ws + 16777216 + 16777216);  // 1.05 MB (within wqT)

  // 1) x -> bf16
  k_cvt_f32_bf16<<<8192, 256, 0, stream>>>(x, xb, 2097152);
  // 2) weight transposes (B^T layout for GEMM)
  k_transpose_cvt<<<dim3(96, 32), 256, 0, stream>>>(qkvw, wqT, 2048, 6144);
  k_transpose_cvt<<<dim3(32, 32), 256, 0, stream>>>(ow, owT, 2048, 2048);
  // 3) QKV projection (128^2 tile, conflict-free LDS), split epilogue
  k_gemm_bt<6144, 2048, 2><<<dim3(48, 32), 256, 0, stream>>>(
      xb, wqT, qkvb, (void*)Qbuf, (void*)Kbuf, (void*)VTbuf);
  // 4) causal flash attention, 2-way kv-split, LDS dbuf pipeline
  k_attn<<<1024, 256, 0, stream>>>(Qbuf, Kbuf, VTbuf, ctxb, oP, mlP);
  // 4b) merge partials for long q-tiles
  k_merge<<<dim3(16, 32), 256, 0, stream>>>(oP, mlP, ctxb);
  // 5) output projection: out fp32 = ctxb @ owT^T + ob
  k_gemm_bt<2048, 2048, 1><<<dim3(16, 32), 256, 0, stream>>>(
      ctxb, owT, ob, (void*)out, nullptr, nullptr);
}